// Round 4
// baseline (215.498 us; speedup 1.0000x reference)
//
#include <hip/hip_runtime.h>
#include <math.h>

#define BATCH 64
#define NN 512
#define DD 128
#define SLOPE 0.2f

typedef unsigned short u16;
typedef short bf16x8 __attribute__((ext_vector_type(8)));
typedef u16 u16x4 __attribute__((ext_vector_type(4)));
typedef u16 u16x8 __attribute__((ext_vector_type(8)));
typedef float f32x4 __attribute__((ext_vector_type(4)));

static __device__ __forceinline__ u16 f2bf(float x) {
    unsigned int u = __float_as_uint(x);
    unsigned int r = (u + 0x7fffu + ((u >> 16) & 1u)) >> 16;
    return (u16)r;
}
static __device__ __forceinline__ float bf2f(u16 h) {
    return __uint_as_float(((unsigned int)h) << 16);
}

// ---------------------------------------------------------------------------
// Kernel prep: block 0 -> W^T hi/lo split (coalesced reads);
// blocks 1..64 -> colsum[b] (for thresh identity mean(EE^T)=||colsum||^2/N^2)
// ---------------------------------------------------------------------------
__global__ __launch_bounds__(256) void k_prep(const float* __restrict__ W,
                                              const float* __restrict__ E,
                                              u16* __restrict__ WtHi,
                                              u16* __restrict__ WtLo,
                                              float* __restrict__ colsum) {
    __shared__ float csr[8][128];
    int t = threadIdx.x;
    if (blockIdx.x == 0) {
        // thread t: n = t&127, k-half = t>>7. Reads coalesced across lanes.
        int n = t & 127, half = t >> 7;
        #pragma unroll
        for (int g = 0; g < 8; ++g) {
            u16x8 hv, lv;
            #pragma unroll
            for (int j = 0; j < 8; ++j) {
                float v = W[(size_t)(half * 64 + g * 8 + j) * DD + n];
                u16 h = f2bf(v);
                hv[j] = h;
                lv[j] = f2bf(v - bf2f(h));
            }
            *(u16x8*)&WtHi[(size_t)n * DD + half * 64 + g * 8] = hv;
            *(u16x8*)&WtLo[(size_t)n * DD + half * 64 + g * 8] = lv;
        }
    } else {
        int b = blockIdx.x - 1;
        int c4 = t & 31, r0 = t >> 5;
        const float* Eb = E + (size_t)b * NN * DD;
        float cp0 = 0.f, cp1 = 0.f, cp2 = 0.f, cp3 = 0.f;
        for (int k = 0; k < 64; ++k) {
            int row = r0 + k * 8;
            float4 v = *(const float4*)&Eb[(size_t)row * DD + c4 * 4];
            cp0 += v.x; cp1 += v.y; cp2 += v.z; cp3 += v.w;
        }
        csr[r0][c4 * 4 + 0] = cp0;
        csr[r0][c4 * 4 + 1] = cp1;
        csr[r0][c4 * 4 + 2] = cp2;
        csr[r0][c4 * 4 + 3] = cp3;
        __syncthreads();
        if (t < 128) {
            float s = 0.f;
            #pragma unroll
            for (int g = 0; g < 8; ++g) s += csr[g][t];
            colsum[b * DD + t] = s;
        }
    }
}

// ---------------------------------------------------------------------------
// Kernel Z: split-bf16 MFMA z = E@W, LDS-free, barrier-free.
// A-frags of E loaded global->register (each element once per block).
// Emits Ebf (bf16 hi of E), zT (bf16 z^T [B][D][N]), el/er fp32.
// ---------------------------------------------------------------------------
__global__ __launch_bounds__(256) void k_z(const float* __restrict__ E,
                                           const u16* __restrict__ WtHi,
                                           const u16* __restrict__ WtLo,
                                           const float* __restrict__ al,
                                           const float* __restrict__ ar,
                                           u16* __restrict__ Ebf,
                                           u16* __restrict__ zT,
                                           float* __restrict__ el,
                                           float* __restrict__ er) {
    int b = blockIdx.y;
    int n0 = blockIdx.x * 64;
    int t = threadIdx.x;
    int w = t >> 6;
    int lane = t & 63;
    int l15 = lane & 15;
    int quad = lane >> 4;

    int row = n0 + w * 16 + l15;
    const float* Er = E + ((size_t)b * NN + row) * DD;

    // load E row fragment, split hi/lo in-register, store Ebf
    bf16x8 ah[4], alo[4];
    #pragma unroll
    for (int ks = 0; ks < 4; ++ks) {
        float4 v0 = *(const float4*)(Er + ks * 32 + quad * 8);
        float4 v1 = *(const float4*)(Er + ks * 32 + quad * 8 + 4);
        float vv[8] = {v0.x, v0.y, v0.z, v0.w, v1.x, v1.y, v1.z, v1.w};
        u16x8 hv, lv;
        #pragma unroll
        for (int j = 0; j < 8; ++j) {
            u16 h = f2bf(vv[j]);
            hv[j] = h;
            lv[j] = f2bf(vv[j] - bf2f(h));
        }
        ah[ks] = (bf16x8)hv;
        alo[ks] = (bf16x8)lv;
        *(u16x8*)&Ebf[((size_t)b * NN + row) * DD + ks * 32 + quad * 8] = hv;
    }

    float elp[4] = {0.f, 0.f, 0.f, 0.f};
    float erp[4] = {0.f, 0.f, 0.f, 0.f};

    #pragma unroll 2
    for (int nt = 0; nt < 8; ++nt) {
        const u16* bh_p = WtHi + (size_t)(nt * 16 + l15) * DD + quad * 8;
        const u16* bl_p = WtLo + (size_t)(nt * 16 + l15) * DD + quad * 8;
        bf16x8 bh[4], bl[4];
        #pragma unroll
        for (int ks = 0; ks < 4; ++ks) {
            bh[ks] = *(const bf16x8*)(bh_p + ks * 32);
            bl[ks] = *(const bf16x8*)(bl_p + ks * 32);
        }
        f32x4 C = (f32x4){0.f, 0.f, 0.f, 0.f};
        #pragma unroll
        for (int ks = 0; ks < 4; ++ks) {
            C = __builtin_amdgcn_mfma_f32_16x16x32_bf16(ah[ks], bh[ks], C, 0, 0, 0);
            C = __builtin_amdgcn_mfma_f32_16x16x32_bf16(alo[ks], bh[ks], C, 0, 0, 0);
            C = __builtin_amdgcn_mfma_f32_16x16x32_bf16(ah[ks], bl[ks], C, 0, 0, 0);
        }
        float av = al[nt * 16 + l15], rv = ar[nt * 16 + l15];
        u16x4 zp;
        #pragma unroll
        for (int r = 0; r < 4; ++r) {
            elp[r] += C[r] * av;
            erp[r] += C[r] * rv;
            zp[r] = f2bf(C[r]);
        }
        *(u16x4*)&zT[((size_t)b * DD + nt * 16 + l15) * NN + n0 + w * 16 + quad * 4] = zp;
    }

    // reduce el/er across the 16 lanes of each quad group
    #pragma unroll
    for (int r = 0; r < 4; ++r) {
        float vl = elp[r], vr = erp[r];
        #pragma unroll
        for (int off = 8; off > 0; off >>= 1) {
            vl += __shfl_down(vl, off);
            vr += __shfl_down(vr, off);
        }
        if (l15 == 0) {
            int node = n0 + w * 16 + quad * 4 + r;
            el[b * NN + node] = vl;
            er[b * NN + node] = vr;
        }
    }
}

// ---------------------------------------------------------------------------
// Kernel main: masked GAT attention, wave-private pipeline, ZERO in-loop
// barriers. Block = (b, 32 dst cols); wave w owns src rows [w*128,(w+1)*128).
// ---------------------------------------------------------------------------
__global__ __launch_bounds__(256, 2) void k_main(const u16* __restrict__ Ebf,
                                                 const u16* __restrict__ zT,
                                                 const float* __restrict__ el,
                                                 const float* __restrict__ er,
                                                 const float* __restrict__ colsum,
                                                 const float* __restrict__ bias,
                                                 float* __restrict__ out) {
    int bid = blockIdx.x;
    // XCD swizzle: all 16 blocks of a batch share one XCD's L2
    int b = (bid & 7) * 8 + (bid >> 7);
    int j0 = ((bid >> 3) & 15) * 32;
    int t = threadIdx.x;
    int w = t >> 6;
    int lane = t & 63;
    int l15 = lane & 15;
    int quad = lane >> 4;

    const u16* Eb = Ebf + (size_t)b * NN * DD;
    const u16* zTb = zT + (size_t)b * DD * NN;

    __shared__ u16 pT[4][32][40];    // per-wave private P^T (32j x 32i, +8 pad)
    __shared__ float hsum[32][132];  // cross-wave H reduction
    __shared__ float zsum[32];
    __shared__ float osum[128];
    __shared__ float tred[2];

    for (int idx = t; idx < 32 * 132; idx += 256) (&hsum[0][0])[idx] = 0.f;
    if (t < 32) zsum[t] = 0.f;

    // thresh = ||colsum||^2 / N^2
    if (t < 128) {
        float c = colsum[b * DD + t];
        float v = c * c;
        #pragma unroll
        for (int off = 32; off > 0; off >>= 1) v += __shfl_down(v, off);
        if ((t & 63) == 0) tred[t >> 6] = v;
    }

    // persistent Ej B-frags
    bf16x8 bEj[2][4];
    #pragma unroll
    for (int jt = 0; jt < 2; ++jt)
        #pragma unroll
        for (int ks = 0; ks < 4; ++ks)
            bEj[jt][ks] = *(const bf16x8*)(Eb + (size_t)(j0 + jt * 16 + l15) * DD + ks * 32 + quad * 8);

    float er_v[2] = { er[b * NN + j0 + l15], er[b * NN + j0 + 16 + l15] };

    f32x4 H[2][8];
    #pragma unroll
    for (int mt = 0; mt < 2; ++mt)
        #pragma unroll
        for (int nt = 0; nt < 8; ++nt) H[mt][nt] = (f32x4){0.f, 0.f, 0.f, 0.f};
    float zpart[2] = {0.f, 0.f};

    __syncthreads();  // init + tred visible; ONLY barrier before epilogue
    float thr = (tred[0] + tred[1]) * (1.0f / ((float)NN * (float)NN));

    #pragma unroll 2
    for (int hh = 0; hh < 4; ++hh) {
        int ih = w * 128 + hh * 32;

        // independent loads up front
        bf16x8 aE[2][4];
        #pragma unroll
        for (int im = 0; im < 2; ++im)
            #pragma unroll
            for (int ks = 0; ks < 4; ++ks)
                aE[im][ks] = *(const bf16x8*)(Eb + (size_t)(ih + im * 16 + l15) * DD + ks * 32 + quad * 8);
        bf16x8 bz[8];
        #pragma unroll
        for (int nt = 0; nt < 8; ++nt)
            bz[nt] = *(const bf16x8*)(zTb + (size_t)(nt * 16 + l15) * NN + ih + quad * 8);
        float4 el4a = *(const float4*)(el + b * NN + ih + quad * 4);
        float4 el4b = *(const float4*)(el + b * NN + ih + 16 + quad * 4);

        // scores
        f32x4 S[2][2];
        S[0][0] = (f32x4){0.f, 0.f, 0.f, 0.f}; S[0][1] = (f32x4){0.f, 0.f, 0.f, 0.f};
        S[1][0] = (f32x4){0.f, 0.f, 0.f, 0.f}; S[1][1] = (f32x4){0.f, 0.f, 0.f, 0.f};
        #pragma unroll
        for (int ks = 0; ks < 4; ++ks)
            #pragma unroll
            for (int im = 0; im < 2; ++im) {
                S[im][0] = __builtin_amdgcn_mfma_f32_16x16x32_bf16(aE[im][ks], bEj[0][ks], S[im][0], 0, 0, 0);
                S[im][1] = __builtin_amdgcn_mfma_f32_16x16x32_bf16(aE[im][ks], bEj[1][ks], S[im][1], 0, 0, 0);
            }

        // mask + max-free exp -> wave-private pT
        #pragma unroll
        for (int im = 0; im < 2; ++im) {
            float elv[4];
            if (im == 0) { elv[0] = el4a.x; elv[1] = el4a.y; elv[2] = el4a.z; elv[3] = el4a.w; }
            else         { elv[0] = el4b.x; elv[1] = el4b.y; elv[2] = el4b.z; elv[3] = el4b.w; }
            #pragma unroll
            for (int jt = 0; jt < 2; ++jt) {
                float ls = 0.f;
                u16x4 pk;
                #pragma unroll
                for (int r = 0; r < 4; ++r) {
                    int ig = ih + im * 16 + quad * 4 + r;
                    int jg = j0 + jt * 16 + l15;
                    float x = elv[r] + er_v[jt];
                    float lg = x > 0.f ? x : SLOPE * x;
                    bool keep = (S[im][jt][r] > thr) || (ig == jg);
                    float pe = keep ? __expf(lg) : 0.f;
                    u16 pb = f2bf(pe);
                    pk[r] = pb;
                    ls += bf2f(pb);
                }
                zpart[jt] += ls;
                *(u16x4*)&pT[w][jt * 16 + l15][im * 16 + quad * 4] = pk;
            }
        }

        // within-wave LDS round-trip: C-layout -> A-layout (lgkmcnt only)
        bf16x8 ap[2];
        #pragma unroll
        for (int mt = 0; mt < 2; ++mt)
            ap[mt] = *(const bf16x8*)&pT[w][mt * 16 + l15][quad * 8];

        // aggregation
        #pragma unroll
        for (int mt = 0; mt < 2; ++mt)
            #pragma unroll
            for (int nt = 0; nt < 8; ++nt)
                H[mt][nt] = __builtin_amdgcn_mfma_f32_16x16x32_bf16(ap[mt], bz[nt], H[mt][nt], 0, 0, 0);
    }

    // ---- epilogue: cross-wave reduce via LDS atomics (once)
    atomicAdd(&zsum[l15], zpart[0]);
    atomicAdd(&zsum[16 + l15], zpart[1]);
    #pragma unroll
    for (int mt = 0; mt < 2; ++mt)
        #pragma unroll
        for (int nt = 0; nt < 8; ++nt)
            #pragma unroll
            for (int r = 0; r < 4; ++r)
                atomicAdd(&hsum[mt * 16 + quad * 4 + r][nt * 16 + l15], H[mt][nt][r]);
    __syncthreads();
    if (t < 32) zsum[t] = 1.0f / zsum[t];  // self-loop guarantees > 0
    __syncthreads();

    int d = t & 127, jh = t >> 7;
    float bsv = bias[d];
    float acc = 0.f;
    #pragma unroll
    for (int q = 0; q < 16; ++q) {
        int j = jh * 16 + q;
        float v = hsum[j][d] * zsum[j] + bsv;
        v = v > 0.f ? v : (__expf(v) - 1.f);
        acc += v;
    }
    if (jh == 1) osum[d] = acc;
    __syncthreads();
    if (t < 128) atomicAdd(&out[b * DD + t], (acc + osum[t]) * (1.0f / NN));
}

// ---------------------------------------------------------------------------
extern "C" void kernel_launch(void* const* d_in, const int* in_sizes, int n_in,
                              void* d_out, int out_size, void* d_ws, size_t ws_size,
                              hipStream_t stream) {
    const float* E    = (const float*)d_in[0];
    const float* W    = (const float*)d_in[1];
    const float* al   = (const float*)d_in[2];
    const float* ar   = (const float*)d_in[3];
    const float* bias = (const float*)d_in[4];
    float* out = (float*)d_out;

    u16* Ebf = (u16*)d_ws;                                     // 8 MB
    u16* zTb = Ebf + (size_t)BATCH * NN * DD;                  // 8 MB
    u16* WtHi = zTb + (size_t)BATCH * NN * DD;                 // 32 KB
    u16* WtLo = WtHi + (size_t)DD * DD;                        // 32 KB
    float* el  = (float*)(WtLo + (size_t)DD * DD);             // 128 KB
    float* er  = el + (size_t)BATCH * NN;                      // 128 KB
    float* colsum = er + (size_t)BATCH * NN;                   // 32 KB

    hipMemsetAsync(d_out, 0, sizeof(float) * (size_t)out_size, stream);

    k_prep<<<dim3(BATCH + 1), dim3(256), 0, stream>>>(W, E, WtHi, WtLo, colsum);
    k_z<<<dim3(NN / 64, BATCH), dim3(256), 0, stream>>>(E, WtHi, WtLo, al, ar,
                                                        Ebf, zTb, el, er);
    k_main<<<dim3(BATCH * NN / 32), dim3(256), 0, stream>>>(Ebf, zTb, el, er,
                                                            colsum, bias, out);
}

// Round 5
// 166.236 us; speedup vs baseline: 1.2963x; 1.2963x over previous
//
#include <hip/hip_runtime.h>
#include <math.h>

#define BATCH 64
#define NN 512
#define DD 128
#define SLOPE 0.2f

typedef unsigned short u16;
typedef short bf16x8 __attribute__((ext_vector_type(8)));
typedef u16 u16x4 __attribute__((ext_vector_type(4)));
typedef u16 u16x8 __attribute__((ext_vector_type(8)));
typedef float f32x4 __attribute__((ext_vector_type(4)));

static __device__ __forceinline__ u16 f2bf(float x) {
    unsigned int u = __float_as_uint(x);
    unsigned int r = (u + 0x7fffu + ((u >> 16) & 1u)) >> 16;
    return (u16)r;
}
static __device__ __forceinline__ float bf2f(u16 h) {
    return __uint_as_float(((unsigned int)h) << 16);
}

// ---------------------------------------------------------------------------
// k_prep: block 0 -> W^T hi/lo split; blocks 1..64 -> colsum[b]
// (thresh identity: mean(E E^T) = ||colsum||^2 / N^2)
// ---------------------------------------------------------------------------
__global__ __launch_bounds__(256) void k_prep(const float* __restrict__ W,
                                              const float* __restrict__ E,
                                              u16* __restrict__ WtHi,
                                              u16* __restrict__ WtLo,
                                              float* __restrict__ colsum) {
    __shared__ float csr[8][128];
    int t = threadIdx.x;
    if (blockIdx.x == 0) {
        int n = t & 127, half = t >> 7;
        #pragma unroll
        for (int g = 0; g < 8; ++g) {
            u16x8 hv, lv;
            #pragma unroll
            for (int j = 0; j < 8; ++j) {
                float v = W[(size_t)(half * 64 + g * 8 + j) * DD + n];
                u16 h = f2bf(v);
                hv[j] = h;
                lv[j] = f2bf(v - bf2f(h));
            }
            *(u16x8*)&WtHi[(size_t)n * DD + half * 64 + g * 8] = hv;
            *(u16x8*)&WtLo[(size_t)n * DD + half * 64 + g * 8] = lv;
        }
    } else {
        int b = blockIdx.x - 1;
        int c4 = t & 31, r0 = t >> 5;
        const float* Eb = E + (size_t)b * NN * DD;
        float cp0 = 0.f, cp1 = 0.f, cp2 = 0.f, cp3 = 0.f;
        for (int k = 0; k < 64; ++k) {
            int row = r0 + k * 8;
            float4 v = *(const float4*)&Eb[(size_t)row * DD + c4 * 4];
            cp0 += v.x; cp1 += v.y; cp2 += v.z; cp3 += v.w;
        }
        csr[r0][c4 * 4 + 0] = cp0;
        csr[r0][c4 * 4 + 1] = cp1;
        csr[r0][c4 * 4 + 2] = cp2;
        csr[r0][c4 * 4 + 3] = cp3;
        __syncthreads();
        if (t < 128) {
            float s = 0.f;
            #pragma unroll
            for (int g = 0; g < 8; ++g) s += csr[g][t];
            colsum[b * DD + t] = s;
        }
    }
}

// ---------------------------------------------------------------------------
// k_z: z = E@W via split-bf16 MFMA. Wave w owns output cols [32w,32w+32),
// W-frags persistent in registers; loops 4 strips of 16 rows (64 rows/block).
// Two independent C chains per strip. Emits Ebf, zT, el, er.
// ---------------------------------------------------------------------------
__global__ __launch_bounds__(256) void k_z(const float* __restrict__ E,
                                           const u16* __restrict__ WtHi,
                                           const u16* __restrict__ WtLo,
                                           const float* __restrict__ al,
                                           const float* __restrict__ ar,
                                           u16* __restrict__ Ebf,
                                           u16* __restrict__ zT,
                                           float* __restrict__ el,
                                           float* __restrict__ er) {
    int bid = blockIdx.x;
    int b = (bid & 7) * 8 + (bid >> 6);   // XCD swizzle
    int rg = (bid >> 3) & 7;              // 64-row group
    int t = threadIdx.x;
    int w = t >> 6;
    int lane = t & 63;
    int l15 = lane & 15;
    int quad = lane >> 4;

    __shared__ float elpart[4][64], erpart[4][64];

    // persistent W^T frags for nt = 2w, 2w+1
    bf16x8 bh[2][4], bl[2][4];
    #pragma unroll
    for (int c = 0; c < 2; ++c) {
        int nt = 2 * w + c;
        #pragma unroll
        for (int ks = 0; ks < 4; ++ks) {
            bh[c][ks] = *(const bf16x8*)(WtHi + (size_t)(nt * 16 + l15) * DD + ks * 32 + quad * 8);
            bl[c][ks] = *(const bf16x8*)(WtLo + (size_t)(nt * 16 + l15) * DD + ks * 32 + quad * 8);
        }
    }
    float a_l[2] = { al[2 * w * 16 + l15], al[(2 * w + 1) * 16 + l15] };
    float a_r[2] = { ar[2 * w * 16 + l15], ar[(2 * w + 1) * 16 + l15] };

    #pragma unroll
    for (int s = 0; s < 4; ++s) {
        int row = rg * 64 + s * 16 + l15;
        const float* Er = E + ((size_t)b * NN + row) * DD;

        bf16x8 ah[4], alo[4];
        #pragma unroll
        for (int ks = 0; ks < 4; ++ks) {
            float4 v0 = *(const float4*)(Er + ks * 32 + quad * 8);
            float4 v1 = *(const float4*)(Er + ks * 32 + quad * 8 + 4);
            float vv[8] = {v0.x, v0.y, v0.z, v0.w, v1.x, v1.y, v1.z, v1.w};
            u16x8 hv, lv;
            #pragma unroll
            for (int j = 0; j < 8; ++j) {
                u16 h = f2bf(vv[j]);
                hv[j] = h;
                lv[j] = f2bf(vv[j] - bf2f(h));
            }
            ah[ks] = (bf16x8)hv;
            alo[ks] = (bf16x8)lv;
            if (w == 0)
                *(u16x8*)&Ebf[((size_t)b * NN + row) * DD + ks * 32 + quad * 8] = hv;
        }

        f32x4 C0 = (f32x4){0.f, 0.f, 0.f, 0.f};
        f32x4 C1 = (f32x4){0.f, 0.f, 0.f, 0.f};
        #pragma unroll
        for (int ks = 0; ks < 4; ++ks) {
            C0 = __builtin_amdgcn_mfma_f32_16x16x32_bf16(ah[ks],  bh[0][ks], C0, 0, 0, 0);
            C1 = __builtin_amdgcn_mfma_f32_16x16x32_bf16(ah[ks],  bh[1][ks], C1, 0, 0, 0);
            C0 = __builtin_amdgcn_mfma_f32_16x16x32_bf16(alo[ks], bh[0][ks], C0, 0, 0, 0);
            C1 = __builtin_amdgcn_mfma_f32_16x16x32_bf16(alo[ks], bh[1][ks], C1, 0, 0, 0);
            C0 = __builtin_amdgcn_mfma_f32_16x16x32_bf16(ah[ks],  bl[0][ks], C0, 0, 0, 0);
            C1 = __builtin_amdgcn_mfma_f32_16x16x32_bf16(ah[ks],  bl[1][ks], C1, 0, 0, 0);
        }

        // zT stores (rows = d, cols = node)
        u16x4 z0, z1;
        #pragma unroll
        for (int r = 0; r < 4; ++r) { z0[r] = f2bf(C0[r]); z1[r] = f2bf(C1[r]); }
        int colbase = rg * 64 + s * 16 + quad * 4;
        *(u16x4*)&zT[((size_t)b * DD + (2 * w) * 16 + l15) * NN + colbase] = z0;
        *(u16x4*)&zT[((size_t)b * DD + (2 * w + 1) * 16 + l15) * NN + colbase] = z1;

        // el/er partials: reduce over the 16 cols this wave owns per nt-pair
        #pragma unroll
        for (int r = 0; r < 4; ++r) {
            float vl = C0[r] * a_l[0] + C1[r] * a_l[1];
            float vr = C0[r] * a_r[0] + C1[r] * a_r[1];
            #pragma unroll
            for (int off = 8; off > 0; off >>= 1) {
                vl += __shfl_down(vl, off);
                vr += __shfl_down(vr, off);
            }
            if (l15 == 0) {
                elpart[w][s * 16 + quad * 4 + r] = vl;
                erpart[w][s * 16 + quad * 4 + r] = vr;
            }
        }
    }
    __syncthreads();
    if (t < 64) {
        float sl = elpart[0][t] + elpart[1][t] + elpart[2][t] + elpart[3][t];
        float sr = erpart[0][t] + erpart[1][t] + erpart[2][t] + erpart[3][t];
        el[b * NN + rg * 64 + t] = sl;
        er[b * NN + rg * 64 + t] = sr;
    }
}

// ---------------------------------------------------------------------------
// k_s: scores -> mask -> exp -> P^T (bf16, [b][j][i]) to global.
// Block = (b, 64-i chunk); wave owns 16 i rows (persistent A-frags);
// loops 16 iters x 2 j-tiles. No inner barriers.
// ---------------------------------------------------------------------------
__global__ __launch_bounds__(256) void k_s(const u16* __restrict__ Ebf,
                                           const float* __restrict__ el,
                                           const float* __restrict__ er,
                                           const float* __restrict__ colsum,
                                           u16* __restrict__ PT) {
    int bid = blockIdx.x;
    int b = (bid & 7) * 8 + (bid >> 6);   // XCD swizzle
    int ic = (bid >> 3) & 7;
    int t = threadIdx.x;
    int w = t >> 6;
    int lane = t & 63;
    int l15 = lane & 15;
    int quad = lane >> 4;
    int ib = ic * 64 + w * 16;

    __shared__ float er_s[NN];
    __shared__ float tred[2];

    if (t < 128) {
        float c = colsum[b * DD + t];
        float v = c * c;
        #pragma unroll
        for (int off = 32; off > 0; off >>= 1) v += __shfl_down(v, off);
        if ((t & 63) == 0) tred[t >> 6] = v;
    }
    for (int idx = t; idx < NN; idx += 256) er_s[idx] = er[b * NN + idx];

    const u16* Eb = Ebf + (size_t)b * NN * DD;
    bf16x8 aE[4];
    #pragma unroll
    for (int ks = 0; ks < 4; ++ks)
        aE[ks] = *(const bf16x8*)(Eb + (size_t)(ib + l15) * DD + ks * 32 + quad * 8);
    float4 el4 = *(const float4*)(el + b * NN + ib + quad * 4);
    float elv[4] = {el4.x, el4.y, el4.z, el4.w};

    __syncthreads();
    float thr = (tred[0] + tred[1]) * (1.0f / ((float)NN * (float)NN));

    u16* PTb = PT + (size_t)b * NN * NN;

    for (int jt2 = 0; jt2 < 16; ++jt2) {
        int j0 = jt2 * 32;
        bf16x8 bEj[2][4];
        #pragma unroll
        for (int jt = 0; jt < 2; ++jt)
            #pragma unroll
            for (int ks = 0; ks < 4; ++ks)
                bEj[jt][ks] = *(const bf16x8*)(Eb + (size_t)(j0 + jt * 16 + l15) * DD + ks * 32 + quad * 8);

        f32x4 S0 = (f32x4){0.f, 0.f, 0.f, 0.f};
        f32x4 S1 = (f32x4){0.f, 0.f, 0.f, 0.f};
        #pragma unroll
        for (int ks = 0; ks < 4; ++ks) {
            S0 = __builtin_amdgcn_mfma_f32_16x16x32_bf16(aE[ks], bEj[0][ks], S0, 0, 0, 0);
            S1 = __builtin_amdgcn_mfma_f32_16x16x32_bf16(aE[ks], bEj[1][ks], S1, 0, 0, 0);
        }

        #pragma unroll
        for (int jt = 0; jt < 2; ++jt) {
            int jg = j0 + jt * 16 + l15;
            float ere = er_s[jg];
            u16x4 pk;
            #pragma unroll
            for (int r = 0; r < 4; ++r) {
                int ig = ib + quad * 4 + r;
                float x = elv[r] + ere;
                float lg = x > 0.f ? x : SLOPE * x;
                float Sv = (jt == 0) ? S0[r] : S1[r];
                bool keep = (Sv > thr) || (ig == jg);
                float pe = keep ? __expf(lg) : 0.f;
                pk[r] = f2bf(pe);
            }
            *(u16x4*)&PTb[(size_t)jg * NN + ib + quad * 4] = pk;
        }
    }
}

// ---------------------------------------------------------------------------
// k_h: h = P^T . z as a pure GEMM (M=64j/block, N=128d, K=512), Z via an
// extra MFMA with B=ones. Epilogue: /Z, +bias, elu, mean over j, atomic out.
// No LDS, no inner barriers.
// ---------------------------------------------------------------------------
__global__ __launch_bounds__(256) void k_h(const u16* __restrict__ PT,
                                           const u16* __restrict__ zT,
                                           const float* __restrict__ bias,
                                           float* __restrict__ out) {
    int bid = blockIdx.x;
    int b = (bid & 7) * 8 + (bid >> 6);   // XCD swizzle
    int jc = (bid >> 3) & 7;
    int t = threadIdx.x;
    int w = t >> 6;
    int lane = t & 63;
    int l15 = lane & 15;
    int quad = lane >> 4;
    int jb = jc * 64 + w * 16;

    const u16* PTb = PT + (size_t)b * NN * NN;
    const u16* zTb = zT + (size_t)b * DD * NN;

    f32x4 C[8];
    #pragma unroll
    for (int nt = 0; nt < 8; ++nt) C[nt] = (f32x4){0.f, 0.f, 0.f, 0.f};
    f32x4 CZ = (f32x4){0.f, 0.f, 0.f, 0.f};
    bf16x8 one8;
    #pragma unroll
    for (int j = 0; j < 8; ++j) one8[j] = (short)0x3F80;  // bf16 1.0

    for (int i0 = 0; i0 < NN; i0 += 64) {
        bf16x8 ap[2];
        #pragma unroll
        for (int ks = 0; ks < 2; ++ks)
            ap[ks] = *(const bf16x8*)(PTb + (size_t)(jb + l15) * NN + i0 + ks * 32 + quad * 8);
        bf16x8 bz[8][2];
        #pragma unroll
        for (int nt = 0; nt < 8; ++nt)
            #pragma unroll
            for (int ks = 0; ks < 2; ++ks)
                bz[nt][ks] = *(const bf16x8*)(zTb + (size_t)(nt * 16 + l15) * NN + i0 + ks * 32 + quad * 8);

        #pragma unroll
        for (int ks = 0; ks < 2; ++ks) {
            CZ = __builtin_amdgcn_mfma_f32_16x16x32_bf16(ap[ks], one8, CZ, 0, 0, 0);
            #pragma unroll
            for (int nt = 0; nt < 8; ++nt)
                C[nt] = __builtin_amdgcn_mfma_f32_16x16x32_bf16(ap[ks], bz[nt][ks], C[nt], 0, 0, 0);
        }
    }

    // epilogue: rows j = jb + quad*4 + r (CZ[r] = Z for those rows)
    float zinv[4];
    #pragma unroll
    for (int r = 0; r < 4; ++r) zinv[r] = 1.0f / CZ[r];  // self-loop > 0

    #pragma unroll
    for (int nt = 0; nt < 8; ++nt) {
        int d = nt * 16 + l15;
        float bsv = bias[d];
        float acc = 0.f;
        #pragma unroll
        for (int r = 0; r < 4; ++r) {
            float v = C[nt][r] * zinv[r] + bsv;
            v = v > 0.f ? v : (__expf(v) - 1.f);
            acc += v;
        }
        acc += __shfl_down(acc, 32);
        acc += __shfl_down(acc, 16);
        if (lane < 16) atomicAdd(&out[b * DD + d], acc * (1.0f / NN));
    }
}

// ---------------------------------------------------------------------------
extern "C" void kernel_launch(void* const* d_in, const int* in_sizes, int n_in,
                              void* d_out, int out_size, void* d_ws, size_t ws_size,
                              hipStream_t stream) {
    const float* E    = (const float*)d_in[0];
    const float* W    = (const float*)d_in[1];
    const float* al   = (const float*)d_in[2];
    const float* ar   = (const float*)d_in[3];
    const float* bias = (const float*)d_in[4];
    float* out = (float*)d_out;

    // ws layout (~51 MB)
    u16* Ebf = (u16*)d_ws;                                     // 8 MB
    u16* zTb = Ebf + (size_t)BATCH * NN * DD;                  // 8 MB
    u16* PT  = zTb + (size_t)BATCH * NN * DD;                  // 33.5 MB
    u16* WtHi = PT + (size_t)BATCH * NN * NN;                  // 32 KB
    u16* WtLo = WtHi + (size_t)DD * DD;                        // 32 KB
    float* el  = (float*)(WtLo + (size_t)DD * DD);             // 128 KB
    float* er  = el + (size_t)BATCH * NN;                      // 128 KB
    float* colsum = er + (size_t)BATCH * NN;                   // 32 KB

    hipMemsetAsync(d_out, 0, sizeof(float) * (size_t)out_size, stream);

    k_prep<<<dim3(BATCH + 1), dim3(256), 0, stream>>>(W, E, WtHi, WtLo, colsum);
    k_z<<<dim3(512), dim3(256), 0, stream>>>(E, WtHi, WtLo, al, ar, Ebf, zTb, el, er);
    k_s<<<dim3(512), dim3(256), 0, stream>>>(Ebf, el, er, colsum, PT);
    k_h<<<dim3(512), dim3(256), 0, stream>>>(PT, zTb, bias, out);
}